// Round 8
// baseline (431.991 us; speedup 1.0000x reference)
//
#include <hip/hip_runtime.h>

#define DEV __device__ __forceinline__

typedef __attribute__((ext_vector_type(8))) short s8v;   // 8 bf16 (4 VGPRs)
typedef __attribute__((ext_vector_type(4))) float f4v;

DEV short f2bf(float f) {
  unsigned u = __builtin_bit_cast(unsigned, f);
  u += 0x7fffu + ((u >> 16) & 1u);   // RNE
  return (short)(u >> 16);
}
DEV float bf2f(short s) {
  unsigned u = ((unsigned)(unsigned short)s) << 16;
  return __builtin_bit_cast(float, u);
}

DEV f4v mfma_16x16x32_bf16(s8v a, s8v b, f4v c) {
  asm("v_mfma_f32_16x16x32_bf16 %0, %1, %2, %0" : "+v"(c) : "v"(a), "v"(b));
  return c;
}

// relu on packed bf16: bf16 bit pattern compares as int16 (negative bf16 =
// negative int16, +/-0 -> 0), so relu == max_i16(bits, 0).
DEV s8v relu8(s8v a) {
#pragma unroll
  for (int i = 0; i < 8; ++i) a[i] = a[i] > (short)0 ? a[i] : (short)0;
  return a;
}

// ---------------------------------------------------------------------------
// Transpose-convert: in [K,N] f32 row-major  ->  out [N,K] bf16 row-major
// ---------------------------------------------------------------------------
__global__ __launch_bounds__(256) void tconv_k(const float* __restrict__ in,
                                               short* __restrict__ out,
                                               int K, int N) {
  __shared__ float t[64][65];
  const int nb = blockIdx.x * 64, kb = blockIdx.y * 64;
  const int c = threadIdx.x & 63, r0 = threadIdx.x >> 6;  // r0: 0..3
#pragma unroll
  for (int rr = 0; rr < 64; rr += 4)
    t[rr + r0][c] = in[(size_t)(kb + rr + r0) * N + nb + c];
  __syncthreads();
#pragma unroll
  for (int rr = 0; rr < 64; rr += 4)
    out[(size_t)(nb + rr + r0) * K + kb + c] = f2bf(t[c][rr + r0]);
}

// ---------------------------------------------------------------------------
// Elementwise convert f32 -> bf16, 4 elems/thread
// ---------------------------------------------------------------------------
__global__ __launch_bounds__(256) void conv_k(const float* __restrict__ in,
                                              short* __restrict__ out, int n4) {
  int i = blockIdx.x * 256 + threadIdx.x;
  if (i >= n4) return;
  float4 v = ((const float4*)in)[i];
  short4 o;
  o.x = f2bf(v.x);
  o.y = f2bf(v.y);
  o.z = f2bf(v.z);
  o.w = f2bf(v.w);
  ((short4*)out)[i] = o;
}

__global__ __launch_bounds__(256) void zero_k(float* p, int n) {
  int i = blockIdx.x * 256 + threadIdx.x;
  if (i < n) p[i] = 0.f;
}

// ---------------------------------------------------------------------------
// agg[d] = sums_em[d]/sums_e[d];  biasEff[j] = b1[j] + sum_d agg[d]*W1[d][j]
// Parallelized: 64 blocks x 256 threads; block owns 16 j's; 16 d-groups of 32
// reduced via LDS. (Old version: 4 blocks = 4 CUs crawling a 2MB read.)
// ---------------------------------------------------------------------------
__global__ __launch_bounds__(256) void finalize_k(const float* __restrict__ sums,
                                                  const float* __restrict__ W1,
                                                  const float* __restrict__ b1,
                                                  float* __restrict__ biasEff) {
  __shared__ float agg[512];
  __shared__ float part[16][16];
  const int tid = threadIdx.x;
  for (int d = tid; d < 512; d += 256) agg[d] = sums[512 + d] / sums[d];
  __syncthreads();
  const int j = blockIdx.x * 16 + (tid & 15);
  const int grp = tid >> 4;                  // 0..15
  float p = 0.f;
#pragma unroll 4
  for (int dd = 0; dd < 32; ++dd) {
    int d = grp * 32 + dd;
    p += agg[d] * W1[(size_t)d * 1024 + j];
  }
  part[grp][tid & 15] = p;
  __syncthreads();
  if (tid < 16) {
    float a = b1[blockIdx.x * 16 + tid];
#pragma unroll
    for (int g = 0; g < 16; ++g) a += part[g][tid];
    biasEff[blockIdx.x * 16 + tid] = a;
  }
}

// ---------------------------------------------------------------------------
// LayerNorm(1024) + relu, in-place on bf16 buffer. 1 wave per row.
// ---------------------------------------------------------------------------
__global__ __launch_bounds__(256) void ln_relu_k(short* __restrict__ z,
                                                 const float* __restrict__ g,
                                                 const float* __restrict__ be) {
  const int row = blockIdx.x * 4 + (threadIdx.x >> 6);
  const int lane = threadIdx.x & 63;
  short* zr = z + (size_t)row * 1024;
  s8v c0 = *(const s8v*)&zr[lane * 8];
  s8v c1 = *(const s8v*)&zr[512 + lane * 8];
  float v[16];
  float s = 0.f, q = 0.f;
#pragma unroll
  for (int i = 0; i < 8; ++i) { v[i] = bf2f(c0[i]); v[8 + i] = bf2f(c1[i]); }
#pragma unroll
  for (int i = 0; i < 16; ++i) { s += v[i]; q += v[i] * v[i]; }
#pragma unroll
  for (int o = 32; o > 0; o >>= 1) { s += __shfl_xor(s, o); q += __shfl_xor(q, o); }
  float mu = s * (1.f / 1024.f);
  float var = q * (1.f / 1024.f) - mu * mu;
  float rs = rsqrtf(var + 1e-5f);
  float gv[16], bv[16];
#pragma unroll
  for (int i = 0; i < 8; ++i) {
    gv[i] = g[lane * 8 + i];      gv[8 + i] = g[512 + lane * 8 + i];
    bv[i] = be[lane * 8 + i];     bv[8 + i] = be[512 + lane * 8 + i];
  }
  s8v o0, o1;
#pragma unroll
  for (int i = 0; i < 8; ++i) {
    o0[i] = f2bf(fmaxf((v[i] - mu) * rs * gv[i] + bv[i], 0.f));
    o1[i] = f2bf(fmaxf((v[8 + i] - mu) * rs * gv[8 + i] + bv[8 + i], 0.f));
  }
  *(s8v*)&zr[lane * 8] = o0;
  *(s8v*)&zr[512 + lane * 8] = o1;
}

// ---------------------------------------------------------------------------
// GEMM: C[M,N] = A[M,K](bf16) * Bt[N,K](bf16)^T + bias, fused epilogues.
// ROUND 8: tile 64x128 (was 128x128) -> 2-4x more blocks (8-16/CU) so TLP
// hides the per-iteration staging drain (occupancy was the limiter: all of
// MfmaUtil/VALUBusy/HBM ~21% at 4 blocks/CU). 4 waves side-by-side (1x4),
// acc[4][2], 12KB LDS, single-buffered r5-verified loop (r7's dbuf was a
// regression: TLP already covers latency, 2x LDS hurt residency).
// Chunk XOR-swizzle retained (both-sides, rule 21). T1 XCD swizzle retained.
// FLAGS: 1=ADD bf16 residual, 2=write f32, 4=write bf16, 8=softmax sums,
//        16=relu applied to A fragments in-register
// ---------------------------------------------------------------------------
#define F_ADD   1
#define F_WF32  2
#define F_WBF   4
#define F_SM    8
#define F_RELUA 16

template <int FLAGS>
__global__ __launch_bounds__(256) void gemm_k(const short* __restrict__ A,
                                              const short* __restrict__ Bt,
                                              const float* __restrict__ bias,
                                              const short* __restrict__ Xin,
                                              short* __restrict__ Cb,
                                              float* __restrict__ Cf,
                                              const float* __restrict__ tptr,
                                              float* __restrict__ sums,
                                              int M, int N, int K) {
  __shared__ short lA[64 * 32];    // 4 KB
  __shared__ short lB[128 * 32];   // 8 KB
  const int tid = threadIdx.x;
  const int lane = tid & 63, wid = tid >> 6;
  const int nwg = gridDim.x * gridDim.y;
  const int wg = blockIdx.y * gridDim.x + blockIdx.x;
  const int swz = (wg & 7) * (nwg >> 3) + (wg >> 3);
  const int bx = swz % gridDim.x, by = swz / gridDim.x;
  const int brow = by * 64, bcol = bx * 128;
  const int l15 = lane & 15, lhi = lane >> 4;
  f4v acc[4][2] = {};

  for (int k0 = 0; k0 < K; k0 += 32) {
    {  // A tile: 64x32 = 4KB = 256 chunks, one per thread
      int chunk = wid * 64 + lane;
      int row = chunk >> 2;
      int sw = (row & 3) ^ ((row >> 2) & 3);
      int kc = ((chunk & 3) ^ sw) << 3;        // swizzled global k-offset
      __builtin_amdgcn_global_load_lds(
          (const __attribute__((address_space(1))) void*)(A + (size_t)(brow + row) * K + k0 + kc),
          (__attribute__((address_space(3))) void*)&lA[(wid * 64) * 8],
          16, 0, 0);
    }
#pragma unroll
    for (int r = 0; r < 2; ++r) {  // B tile: 128x32 = 8KB = 512 chunks
      int chunk = r * 256 + wid * 64 + lane;
      int row = chunk >> 2;
      int sw = (row & 3) ^ ((row >> 2) & 3);
      int kc = ((chunk & 3) ^ sw) << 3;
      __builtin_amdgcn_global_load_lds(
          (const __attribute__((address_space(1))) void*)(Bt + (size_t)(bcol + row) * K + k0 + kc),
          (__attribute__((address_space(3))) void*)&lB[(r * 256 + wid * 64) * 8],
          16, 0, 0);
    }
    __syncthreads();
    s8v af[4], bfr[2];
#pragma unroll
    for (int i = 0; i < 4; ++i) {
      const int rowA = i * 16 + l15;
      const int sw = (rowA & 3) ^ ((rowA >> 2) & 3);
      af[i] = *(const s8v*)&lA[rowA * 32 + ((lhi ^ sw) << 3)];
      if (FLAGS & F_RELUA) af[i] = relu8(af[i]);
    }
#pragma unroll
    for (int j = 0; j < 2; ++j) {
      const int rowB = wid * 32 + j * 16 + l15;
      const int sw = (rowB & 3) ^ ((rowB >> 2) & 3);
      bfr[j] = *(const s8v*)&lB[rowB * 32 + ((lhi ^ sw) << 3)];
    }
#pragma unroll
    for (int mi = 0; mi < 4; ++mi)
#pragma unroll
      for (int ni = 0; ni < 2; ++ni)
        acc[mi][ni] = mfma_16x16x32_bf16(af[mi], bfr[ni], acc[mi][ni]);
    __syncthreads();
  }

  // ---- epilogue ----
  const float tv = (FLAGS & F_SM) ? tptr[0] : 0.f;
  float* sred = (float*)lA;  // repurpose LDS: [2][128] block-level partials
  if (FLAGS & F_SM) {
    sred[tid] = 0.f;
    __syncthreads();
  }
#pragma unroll
  for (int ni = 0; ni < 2; ++ni) {
    int col = bcol + wid * 32 + ni * 16 + l15;
    float bv = bias[col];
    float se = 0.f, sem = 0.f;
#pragma unroll
    for (int mi = 0; mi < 4; ++mi) {
#pragma unroll
      for (int r = 0; r < 4; ++r) {
        int row = brow + mi * 16 + lhi * 4 + r;
        size_t idx = (size_t)row * N + col;
        float v = acc[mi][ni][r] + bv;
        if (FLAGS & F_ADD) v += bf2f(Xin[idx]);
        if (FLAGS & F_WF32) Cf[idx] = v;
        if (FLAGS & F_WBF) Cb[idx] = f2bf(v);
        if (FLAGS & F_SM) {
          float m = fmaxf(v, 0.f) + 1e-7f;
          float e = __expf(tv * m);
          se += e;
          sem += e * m;
        }
      }
    }
    if (FLAGS & F_SM) {
      se += __shfl_xor(se, 16);   se += __shfl_xor(se, 32);
      sem += __shfl_xor(sem, 16); sem += __shfl_xor(sem, 32);
      if (lhi == 0) {
        atomicAdd(&sred[wid * 32 + ni * 16 + l15], se);
        atomicAdd(&sred[128 + wid * 32 + ni * 16 + l15], sem);
      }
    }
  }
  if (FLAGS & F_SM) {
    __syncthreads();
    int v = tid >> 7, c = tid & 127;
    atomicAdd(&sums[v * 512 + bcol + c], sred[v * 128 + c]);
  }
}

// ---------------------------------------------------------------------------
extern "C" void kernel_launch(void* const* d_in, const int* in_sizes, int n_in,
                              void* d_out, int out_size, void* d_ws,
                              size_t ws_size, hipStream_t stream) {
  (void)in_sizes; (void)n_in; (void)out_size; (void)ws_size;
  const float* batch = (const float*)d_in[0];
  const float* W_enc = (const float*)d_in[1];
  const float* b_enc = (const float*)d_in[2];
  const float* Wf    = (const float*)d_in[3];
  const float* bfv   = (const float*)d_in[4];
  const float* tptr[2] = {(const float*)d_in[5],  (const float*)d_in[12]};
  const float* W1[2]   = {(const float*)d_in[6],  (const float*)d_in[13]};
  const float* b1[2]   = {(const float*)d_in[7],  (const float*)d_in[14]};
  const float* g[2]    = {(const float*)d_in[8],  (const float*)d_in[15]};
  const float* be[2]   = {(const float*)d_in[9],  (const float*)d_in[16]};
  const float* W2[2]   = {(const float*)d_in[10], (const float*)d_in[17]};
  const float* b2[2]   = {(const float*)d_in[11], (const float*)d_in[18]};
  float* out = (float*)d_out;

  const int M = 32768;
  char* ws = (char*)d_ws;
  size_t off = 0;
  auto alloc = [&](size_t bytes) -> char* {
    char* p = ws + off;
    off += (bytes + 255) & ~(size_t)255;
    return p;
  };
  short* xbf    = (short*)alloc((size_t)M * 512 * 2);   // bf16 residual stream x
  short* zbuf   = (short*)alloc((size_t)M * 1024 * 2);  // bf16 z1 / z
  short* bbuf   = (short*)alloc((size_t)M * 64 * 2);    // bf16 batch (encoder A)
  short* wencT  = (short*)alloc(512 * 64 * 2);
  short* w1T0   = (short*)alloc(1024 * 512 * 2);
  short* w2T0   = (short*)alloc(512 * 1024 * 2);
  short* w1T1   = (short*)alloc(1024 * 512 * 2);
  short* w2T1   = (short*)alloc(512 * 1024 * 2);
  short* wfT    = (short*)alloc(128 * 512 * 2);
  float* sums   = (float*)alloc(2 * 1024 * 4);          // [layer][e(512), em(512)]
  float* biasEff= (float*)alloc(1024 * 4);
  short* w1T[2] = {w1T0, w1T1};
  short* w2T[2] = {w2T0, w2T1};

  // Weight transpose-converts (f32 [K,N] -> bf16 [N,K])
  tconv_k<<<dim3(512 / 64, 64 / 64), 256, 0, stream>>>(W_enc, wencT, 64, 512);
  tconv_k<<<dim3(1024 / 64, 512 / 64), 256, 0, stream>>>(W1[0], w1T[0], 512, 1024);
  tconv_k<<<dim3(512 / 64, 1024 / 64), 256, 0, stream>>>(W2[0], w2T[0], 1024, 512);
  tconv_k<<<dim3(1024 / 64, 512 / 64), 256, 0, stream>>>(W1[1], w1T[1], 512, 1024);
  tconv_k<<<dim3(512 / 64, 1024 / 64), 256, 0, stream>>>(W2[1], w2T[1], 1024, 512);
  tconv_k<<<dim3(128 / 64, 512 / 64), 256, 0, stream>>>(Wf, wfT, 512, 128);

  // batch -> bf16
  conv_k<<<(M * 64 / 4 + 255) / 256, 256, 0, stream>>>(batch, bbuf, M * 64 / 4);
  // zero softmax accumulators (ws is poisoned before every call)
  zero_k<<<(2048 + 255) / 256, 256, 0, stream>>>(sums, 2048);

  // Encoder: x = batch @ W_enc + b_enc -> bf16 x, fused softmax sums (l0).
  gemm_k<F_WBF | F_SM><<<dim3(512 / 128, M / 64), 256, 0, stream>>>(
      bbuf, wencT, b_enc, nullptr, xbf, nullptr, tptr[0], sums, M, 512, 64);

  for (int l = 0; l < 2; ++l) {
    // biasEff = b1 + agg @ W1
    finalize_k<<<64, 256, 0, stream>>>(sums + l * 1024, W1[l], b1[l], biasEff);
    // z1 = relu(x) @ W1 + biasEff  (bf16; relu applied on A fragments)
    gemm_k<F_WBF | F_RELUA><<<dim3(1024 / 128, M / 64), 256, 0, stream>>>(
        xbf, w1T[l], biasEff, nullptr, zbuf, nullptr, nullptr, nullptr,
        M, 1024, 512);
    // z = relu(LN(z1)) in-place
    ln_relu_k<<<M / 4, 256, 0, stream>>>(zbuf, g[l], be[l]);
    // x = bf16(x + z @ W2 + b2), in-place on xbf; layer 0 also sums(l1)
    if (l == 0) {
      gemm_k<F_ADD | F_WBF | F_SM><<<dim3(512 / 128, M / 64), 256, 0, stream>>>(
          zbuf, w2T[l], b2[l], xbf, xbf, nullptr, tptr[1], sums + 1024,
          M, 512, 1024);
    } else {
      gemm_k<F_ADD | F_WBF><<<dim3(512 / 128, M / 64), 256, 0, stream>>>(
          zbuf, w2T[l], b2[l], xbf, xbf, nullptr, nullptr, nullptr,
          M, 512, 1024);
    }
  }

  // out = relu(x) @ Wf + bf  (relu on A fragments)
  gemm_k<F_WF32 | F_RELUA><<<dim3(128 / 128, M / 64), 256, 0, stream>>>(
      xbf, wfT, bfv, nullptr, nullptr, out, nullptr, nullptr, M, 128, 512);
}

// Round 9
// 371.569 us; speedup vs baseline: 1.1626x; 1.1626x over previous
//
#include <hip/hip_runtime.h>

#define DEV __device__ __forceinline__

typedef __attribute__((ext_vector_type(8))) short s8v;   // 8 bf16 (4 VGPRs)
typedef __attribute__((ext_vector_type(4))) float f4v;

DEV short f2bf(float f) {
  unsigned u = __builtin_bit_cast(unsigned, f);
  u += 0x7fffu + ((u >> 16) & 1u);   // RNE
  return (short)(u >> 16);
}
DEV float bf2f(short s) {
  unsigned u = ((unsigned)(unsigned short)s) << 16;
  return __builtin_bit_cast(float, u);
}

DEV f4v mfma_16x16x32_bf16(s8v a, s8v b, f4v c) {
  asm("v_mfma_f32_16x16x32_bf16 %0, %1, %2, %0" : "+v"(c) : "v"(a), "v"(b));
  return c;
}

// relu on packed bf16: bf16 bit pattern compares as int16 (negative bf16 =
// negative int16, +/-0 -> 0), so relu == max_i16(bits, 0).
DEV s8v relu8(s8v a) {
#pragma unroll
  for (int i = 0; i < 8; ++i) a[i] = a[i] > (short)0 ? a[i] : (short)0;
  return a;
}

// ---------------------------------------------------------------------------
// Transpose-convert: in [K,N] f32 row-major  ->  out [N,K] bf16 row-major
// ---------------------------------------------------------------------------
__global__ __launch_bounds__(256) void tconv_k(const float* __restrict__ in,
                                               short* __restrict__ out,
                                               int K, int N) {
  __shared__ float t[64][65];
  const int nb = blockIdx.x * 64, kb = blockIdx.y * 64;
  const int c = threadIdx.x & 63, r0 = threadIdx.x >> 6;  // r0: 0..3
#pragma unroll
  for (int rr = 0; rr < 64; rr += 4)
    t[rr + r0][c] = in[(size_t)(kb + rr + r0) * N + nb + c];
  __syncthreads();
#pragma unroll
  for (int rr = 0; rr < 64; rr += 4)
    out[(size_t)(nb + rr + r0) * K + kb + c] = f2bf(t[c][rr + r0]);
}

// ---------------------------------------------------------------------------
// Elementwise convert f32 -> bf16, 4 elems/thread
// ---------------------------------------------------------------------------
__global__ __launch_bounds__(256) void conv_k(const float* __restrict__ in,
                                              short* __restrict__ out, int n4) {
  int i = blockIdx.x * 256 + threadIdx.x;
  if (i >= n4) return;
  float4 v = ((const float4*)in)[i];
  short4 o;
  o.x = f2bf(v.x);
  o.y = f2bf(v.y);
  o.z = f2bf(v.z);
  o.w = f2bf(v.w);
  ((short4*)out)[i] = o;
}

__global__ __launch_bounds__(256) void zero_k(float* p, int n) {
  int i = blockIdx.x * 256 + threadIdx.x;
  if (i < n) p[i] = 0.f;
}

// ---------------------------------------------------------------------------
// agg[d] = sums_em[d]/sums_e[d];  biasEff[j] = b1[j] + sum_d agg[d]*W1[d][j]
// 64 blocks x 256 threads; block owns 16 j's; 16 d-groups of 32 via LDS.
// ---------------------------------------------------------------------------
__global__ __launch_bounds__(256) void finalize_k(const float* __restrict__ sums,
                                                  const float* __restrict__ W1,
                                                  const float* __restrict__ b1,
                                                  float* __restrict__ biasEff) {
  __shared__ float agg[512];
  __shared__ float part[16][16];
  const int tid = threadIdx.x;
  for (int d = tid; d < 512; d += 256) agg[d] = sums[512 + d] / sums[d];
  __syncthreads();
  const int j = blockIdx.x * 16 + (tid & 15);
  const int grp = tid >> 4;                  // 0..15
  float p = 0.f;
#pragma unroll 4
  for (int dd = 0; dd < 32; ++dd) {
    int d = grp * 32 + dd;
    p += agg[d] * W1[(size_t)d * 1024 + j];
  }
  part[grp][tid & 15] = p;
  __syncthreads();
  if (tid < 16) {
    float a = b1[blockIdx.x * 16 + tid];
#pragma unroll
    for (int g = 0; g < 16; ++g) a += part[g][tid];
    biasEff[blockIdx.x * 16 + tid] = a;
  }
}

// ---------------------------------------------------------------------------
// LayerNorm(1024) + relu, in-place on bf16 buffer. 1 wave per row.
// ---------------------------------------------------------------------------
__global__ __launch_bounds__(256) void ln_relu_k(short* __restrict__ z,
                                                 const float* __restrict__ g,
                                                 const float* __restrict__ be) {
  const int row = blockIdx.x * 4 + (threadIdx.x >> 6);
  const int lane = threadIdx.x & 63;
  short* zr = z + (size_t)row * 1024;
  s8v c0 = *(const s8v*)&zr[lane * 8];
  s8v c1 = *(const s8v*)&zr[512 + lane * 8];
  float v[16];
  float s = 0.f, q = 0.f;
#pragma unroll
  for (int i = 0; i < 8; ++i) { v[i] = bf2f(c0[i]); v[8 + i] = bf2f(c1[i]); }
#pragma unroll
  for (int i = 0; i < 16; ++i) { s += v[i]; q += v[i] * v[i]; }
#pragma unroll
  for (int o = 32; o > 0; o >>= 1) { s += __shfl_xor(s, o); q += __shfl_xor(q, o); }
  float mu = s * (1.f / 1024.f);
  float var = q * (1.f / 1024.f) - mu * mu;
  float rs = rsqrtf(var + 1e-5f);
  float gv[16], bv[16];
#pragma unroll
  for (int i = 0; i < 8; ++i) {
    gv[i] = g[lane * 8 + i];      gv[8 + i] = g[512 + lane * 8 + i];
    bv[i] = be[lane * 8 + i];     bv[8 + i] = be[512 + lane * 8 + i];
  }
  s8v o0, o1;
#pragma unroll
  for (int i = 0; i < 8; ++i) {
    o0[i] = f2bf(fmaxf((v[i] - mu) * rs * gv[i] + bv[i], 0.f));
    o1[i] = f2bf(fmaxf((v[8 + i] - mu) * rs * gv[8 + i] + bv[8 + i], 0.f));
  }
  *(s8v*)&zr[lane * 8] = o0;
  *(s8v*)&zr[512 + lane * 8] = o1;
}

// ---------------------------------------------------------------------------
// GEMM: C[M,N] = A[M,K](bf16) * Bt[N,K](bf16)^T + bias, fused epilogues.
// 128x128 tile, 4 waves (2x2), 16x16x32 MFMA, global_load_lds.
// ROUND 9 SINGLE CHANGE vs r6-verified loop: BK 32 -> 64. Halves the
// stage-drain+barrier pairs (the measured bottleneck: r7 dbuf and r8
// smaller-tile both regressed; per-K-step overhead dominates) and doubles
// MFMA per barrier (32/wave/step). LDS 32 KB single-buffered. Fragments
// loaded per-kk to keep VGPR in the <=128 band. Swizzle upgraded to full
// 8-residue form (8 chunks/row): LDS slot s holds global chunk s^(row&7),
// applied at stage (global source) and read (slot index) -- involution.
// K-accumulation order identical to BK=32 (kk inner, sequential K).
// T1 XCD-chunked swizzle (nwg % 8 == 0 for every launch here).
// FLAGS: 1=ADD bf16 residual, 2=write f32, 4=write bf16, 8=softmax sums,
//        16=relu applied to A fragments in-register
// ---------------------------------------------------------------------------
#define F_ADD   1
#define F_WF32  2
#define F_WBF   4
#define F_SM    8
#define F_RELUA 16

template <int FLAGS>
__global__ __launch_bounds__(256) void gemm_k(const short* __restrict__ A,
                                              const short* __restrict__ Bt,
                                              const float* __restrict__ bias,
                                              const short* __restrict__ Xin,
                                              short* __restrict__ Cb,
                                              float* __restrict__ Cf,
                                              const float* __restrict__ tptr,
                                              float* __restrict__ sums,
                                              int M, int N, int K) {
  __shared__ short lA[128 * 64];   // 16 KB
  __shared__ short lB[128 * 64];   // 16 KB
  const int tid = threadIdx.x;
  const int lane = tid & 63, wid = tid >> 6;
  const int wr = wid >> 1, wc = wid & 1;
  const int nwg = gridDim.x * gridDim.y;
  const int wg = blockIdx.y * gridDim.x + blockIdx.x;
  const int swz = (wg & 7) * (nwg >> 3) + (wg >> 3);
  const int bx = swz % gridDim.x, by = swz / gridDim.x;
  const int brow = by * 128, bcol = bx * 128;
  const int l15 = lane & 15, lhi = lane >> 4;
  f4v acc[4][4] = {};

  for (int k0 = 0; k0 < K; k0 += 64) {
    // Stage 128x64 A and B tiles: 1024 chunks each, 4 per thread per matrix.
#pragma unroll
    for (int r = 0; r < 4; ++r) {
      int chunk = r * 256 + tid;             // = r*256 + wid*64 + lane
      int row = chunk >> 3;
      int kc = ((chunk & 7) ^ (row & 7)) << 3;   // swizzled global k-offset
      const short* ga = A + (size_t)(brow + row) * K + (k0 + kc);
      const short* gb = Bt + (size_t)(bcol + row) * K + (k0 + kc);
      __builtin_amdgcn_global_load_lds(
          (const __attribute__((address_space(1))) void*)ga,
          (__attribute__((address_space(3))) void*)&lA[(r * 256 + wid * 64) * 8],
          16, 0, 0);
      __builtin_amdgcn_global_load_lds(
          (const __attribute__((address_space(1))) void*)gb,
          (__attribute__((address_space(3))) void*)&lB[(r * 256 + wid * 64) * 8],
          16, 0, 0);
    }
    __syncthreads();
#pragma unroll
    for (int kk = 0; kk < 2; ++kk) {
      s8v af[4], bfr[4];
#pragma unroll
      for (int i = 0; i < 4; ++i) {
        const int rowA = wr * 64 + i * 16 + l15;
        const int rowB = wc * 64 + i * 16 + l15;
        const int cA = ((kk * 4 + lhi) ^ (rowA & 7)) << 3;
        const int cB = ((kk * 4 + lhi) ^ (rowB & 7)) << 3;
        af[i]  = *(const s8v*)&lA[rowA * 64 + cA];
        bfr[i] = *(const s8v*)&lB[rowB * 64 + cB];
        if (FLAGS & F_RELUA) af[i] = relu8(af[i]);
      }
#pragma unroll
      for (int mi = 0; mi < 4; ++mi)
#pragma unroll
        for (int ni = 0; ni < 4; ++ni)
          acc[mi][ni] = mfma_16x16x32_bf16(af[mi], bfr[ni], acc[mi][ni]);
    }
    __syncthreads();
  }

  // ---- epilogue ----
  const float tv = (FLAGS & F_SM) ? tptr[0] : 0.f;
  float* sred = (float*)lA;  // repurpose LDS: [2][128] block-level partials
  if (FLAGS & F_SM) {
    sred[tid] = 0.f;
    __syncthreads();
  }
#pragma unroll
  for (int ni = 0; ni < 4; ++ni) {
    int col = bcol + wc * 64 + ni * 16 + l15;
    float bv = bias[col];
    float se = 0.f, sem = 0.f;
#pragma unroll
    for (int mi = 0; mi < 4; ++mi) {
#pragma unroll
      for (int r = 0; r < 4; ++r) {
        int row = brow + wr * 64 + mi * 16 + lhi * 4 + r;
        size_t idx = (size_t)row * N + col;
        float v = acc[mi][ni][r] + bv;
        if (FLAGS & F_ADD) v += bf2f(Xin[idx]);
        if (FLAGS & F_WF32) Cf[idx] = v;
        if (FLAGS & F_WBF) Cb[idx] = f2bf(v);
        if (FLAGS & F_SM) {
          float m = fmaxf(v, 0.f) + 1e-7f;
          float e = __expf(tv * m);
          se += e;
          sem += e * m;
        }
      }
    }
    if (FLAGS & F_SM) {
      se += __shfl_xor(se, 16);   se += __shfl_xor(se, 32);
      sem += __shfl_xor(sem, 16); sem += __shfl_xor(sem, 32);
      if (lhi == 0) {
        atomicAdd(&sred[wc * 64 + ni * 16 + l15], se);
        atomicAdd(&sred[128 + wc * 64 + ni * 16 + l15], sem);
      }
    }
  }
  if (FLAGS & F_SM) {
    __syncthreads();
    int v = tid >> 7, c = tid & 127;
    atomicAdd(&sums[v * 512 + bcol + c], sred[v * 128 + c]);
  }
}

// ---------------------------------------------------------------------------
extern "C" void kernel_launch(void* const* d_in, const int* in_sizes, int n_in,
                              void* d_out, int out_size, void* d_ws,
                              size_t ws_size, hipStream_t stream) {
  (void)in_sizes; (void)n_in; (void)out_size; (void)ws_size;
  const float* batch = (const float*)d_in[0];
  const float* W_enc = (const float*)d_in[1];
  const float* b_enc = (const float*)d_in[2];
  const float* Wf    = (const float*)d_in[3];
  const float* bfv   = (const float*)d_in[4];
  const float* tptr[2] = {(const float*)d_in[5],  (const float*)d_in[12]};
  const float* W1[2]   = {(const float*)d_in[6],  (const float*)d_in[13]};
  const float* b1[2]   = {(const float*)d_in[7],  (const float*)d_in[14]};
  const float* g[2]    = {(const float*)d_in[8],  (const float*)d_in[15]};
  const float* be[2]   = {(const float*)d_in[9],  (const float*)d_in[16]};
  const float* W2[2]   = {(const float*)d_in[10], (const float*)d_in[17]};
  const float* b2[2]   = {(const float*)d_in[11], (const float*)d_in[18]};
  float* out = (float*)d_out;

  const int M = 32768;
  char* ws = (char*)d_ws;
  size_t off = 0;
  auto alloc = [&](size_t bytes) -> char* {
    char* p = ws + off;
    off += (bytes + 255) & ~(size_t)255;
    return p;
  };
  short* xbf    = (short*)alloc((size_t)M * 512 * 2);   // bf16 residual stream x
  short* zbuf   = (short*)alloc((size_t)M * 1024 * 2);  // bf16 z1 / z
  short* bbuf   = (short*)alloc((size_t)M * 64 * 2);    // bf16 batch (encoder A)
  short* wencT  = (short*)alloc(512 * 64 * 2);
  short* w1T0   = (short*)alloc(1024 * 512 * 2);
  short* w2T0   = (short*)alloc(512 * 1024 * 2);
  short* w1T1   = (short*)alloc(1024 * 512 * 2);
  short* w2T1   = (short*)alloc(512 * 1024 * 2);
  short* wfT    = (short*)alloc(128 * 512 * 2);
  float* sums   = (float*)alloc(2 * 1024 * 4);          // [layer][e(512), em(512)]
  float* biasEff= (float*)alloc(1024 * 4);
  short* w1T[2] = {w1T0, w1T1};
  short* w2T[2] = {w2T0, w2T1};

  // Weight transpose-converts (f32 [K,N] -> bf16 [N,K])
  tconv_k<<<dim3(512 / 64, 64 / 64), 256, 0, stream>>>(W_enc, wencT, 64, 512);
  tconv_k<<<dim3(1024 / 64, 512 / 64), 256, 0, stream>>>(W1[0], w1T[0], 512, 1024);
  tconv_k<<<dim3(512 / 64, 1024 / 64), 256, 0, stream>>>(W2[0], w2T[0], 1024, 512);
  tconv_k<<<dim3(1024 / 64, 512 / 64), 256, 0, stream>>>(W1[1], w1T[1], 512, 1024);
  tconv_k<<<dim3(512 / 64, 1024 / 64), 256, 0, stream>>>(W2[1], w2T[1], 1024, 512);
  tconv_k<<<dim3(128 / 64, 512 / 64), 256, 0, stream>>>(Wf, wfT, 512, 128);

  // batch -> bf16
  conv_k<<<(M * 64 / 4 + 255) / 256, 256, 0, stream>>>(batch, bbuf, M * 64 / 4);
  // zero softmax accumulators (ws is poisoned before every call)
  zero_k<<<(2048 + 255) / 256, 256, 0, stream>>>(sums, 2048);

  // Encoder: x = batch @ W_enc + b_enc -> bf16 x, fused softmax sums (l0).
  gemm_k<F_WBF | F_SM><<<dim3(512 / 128, M / 128), 256, 0, stream>>>(
      bbuf, wencT, b_enc, nullptr, xbf, nullptr, tptr[0], sums, M, 512, 64);

  for (int l = 0; l < 2; ++l) {
    // biasEff = b1 + agg @ W1
    finalize_k<<<64, 256, 0, stream>>>(sums + l * 1024, W1[l], b1[l], biasEff);
    // z1 = relu(x) @ W1 + biasEff  (bf16; relu applied on A fragments)
    gemm_k<F_WBF | F_RELUA><<<dim3(1024 / 128, M / 128), 256, 0, stream>>>(
        xbf, w1T[l], biasEff, nullptr, zbuf, nullptr, nullptr, nullptr,
        M, 1024, 512);
    // z = relu(LN(z1)) in-place
    ln_relu_k<<<M / 4, 256, 0, stream>>>(zbuf, g[l], be[l]);
    // x = bf16(x + z @ W2 + b2), in-place on xbf; layer 0 also sums(l1)
    if (l == 0) {
      gemm_k<F_ADD | F_WBF | F_SM><<<dim3(512 / 128, M / 128), 256, 0, stream>>>(
          zbuf, w2T[l], b2[l], xbf, xbf, nullptr, tptr[1], sums + 1024,
          M, 512, 1024);
    } else {
      gemm_k<F_ADD | F_WBF><<<dim3(512 / 128, M / 128), 256, 0, stream>>>(
          zbuf, w2T[l], b2[l], xbf, xbf, nullptr, nullptr, nullptr,
          M, 512, 1024);
    }
  }

  // out = relu(x) @ Wf + bf  (relu on A fragments)
  gemm_k<F_WF32 | F_RELUA><<<dim3(128 / 128, M / 128), 256, 0, stream>>>(
      xbf, wfT, bfv, nullptr, nullptr, out, nullptr, nullptr, M, 128, 512);
}